// Round 8
// baseline (389.799 us; speedup 1.0000x reference)
//
#include <hip/hip_runtime.h>
#include <math.h>

#define L_NUM 4
#define K_CB  2048
#define D_DIM 256
#define N_ROWS 32768
#define ROWS_B 128        // rows per block
#define CAP 40            // per-row candidate slots (LDS)
#define WACC  0.12f       // collect window (>= 2x worst-case fp16 dot err ~0.032)
#define WACC2 0.125f      // filter window (collect + packing quantization margin)

typedef _Float16 half8 __attribute__((ext_vector_type(8)));
typedef _Float16 half4v __attribute__((ext_vector_type(4)));
typedef float f32x16 __attribute__((ext_vector_type(16)));

__device__ __forceinline__ void gl_lds16(const void* g, void* l) {
  __builtin_amdgcn_global_load_lds(
      (const __attribute__((address_space(1))) void*)g,
      (__attribute__((address_space(3))) void*)l, 16, 0, 0);
}
// monotone float<->uint encoding for atomicMax on floats
__device__ __forceinline__ unsigned fenc(float f) {
  unsigned u = __float_as_uint(f);
  return (u & 0x80000000u) ? ~u : (u | 0x80000000u);
}
__device__ __forceinline__ float fdec(unsigned k) {
  unsigned u = (k & 0x80000000u) ? (k ^ 0x80000000u) : ~k;
  return __uint_as_float(u);
}

// ---------- prep: cbn fp32 (row-major) + cb16 image ----------
// chunk c (32/layer, 32 KB) = cols [(c>>3)*512, +512), K-halves [(c&7)*32, +32)
// within chunk: [4 subslots][512 cols][8 halves]
__global__ __launch_bounds__(64)
void prep_all_kernel(const float* __restrict__ cb,
                     float* __restrict__ cbn,
                     _Float16* __restrict__ cb16) {
  const int b = blockIdx.x;            // l*2048 + k
  const int k = b & 2047, l = b >> 11;
  const int lane = threadIdx.x;        // 4 dims each
  float4 v = reinterpret_cast<const float4*>(cb + (size_t)b * D_DIM)[lane];
  float s = v.x*v.x + v.y*v.y + v.z*v.z + v.w*v.w;
  #pragma unroll
  for (int m = 1; m < 64; m <<= 1) s += __shfl_xor(s, m, 64);
  const float den = fmaxf(sqrtf(s), 1e-12f);
  v.x /= den; v.y /= den; v.z /= den; v.w /= den;   // true division = reference rounding
  reinterpret_cast<float4*>(cbn + (size_t)b * D_DIM)[lane] = v;
  half4v h;
  h[0] = (_Float16)v.x; h[1] = (_Float16)v.y; h[2] = (_Float16)v.z; h[3] = (_Float16)v.w;
  const int ct = k >> 9, col = k & 511;
  const int kc    = lane >> 3;             // dim/32  -> K-chunk
  const int sslot = (lane >> 1) & 3;       // (dim&31)/8
  const int rem   = (lane & 1) * 4;        // dim&7
  const size_t off = (size_t)l * (K_CB * D_DIM)
                   + (size_t)(ct * 8 + kc) * 16384
                   + (size_t)sslot * 4096 + (size_t)col * 8 + rem;
  *(half4v*)(cb16 + off) = h;
}

#define COLL(ACC, BI, MROW, THR, CT) \
  _Pragma("unroll") \
  for (int rg = 0; rg < 16; ++rg) { \
    const float v_ = (ACC)[rg]; \
    if (v_ >= (THR)) { \
      const unsigned q_ = (unsigned)((v_ + 64.f) * 16384.f); \
      const unsigned ci_ = (unsigned)((CT)*512 + colg*128 + (BI)*32 \
                                      + 4*hl + (rg & 3) + 8*(rg >> 2)); \
      const unsigned pk_ = (q_ << 11) | ci_; \
      atomicMax(&bestp[(MROW)], pk_); \
      const int slot_ = atomicAdd(&cn[(MROW)], 1); \
      if (slot_ < CAP) cp[(MROW)*CAP + slot_] = pk_; \
    } \
  }

__device__ __forceinline__ float vmax16_4(const f32x16& a, const f32x16& b,
                                          const f32x16& c, const f32x16& d) {
  float m = -INFINITY;
  #pragma unroll
  for (int i = 0; i < 16; ++i)
    m = fmaxf(m, fmaxf(fmaxf(a[i], b[i]), fmaxf(c[i], d[i])));
  return m;
}

// ---------- fused: 128 rows/block, counted-vmcnt pipeline, 4 layers ----------
__global__ __launch_bounds__(512, 2)
void rq_fused_kernel(const float* __restrict__ x,
                     const float* __restrict__ cb,
                     const float* __restrict__ cbn,
                     const _Float16* __restrict__ cb16,
                     float* __restrict__ out_ids,
                     float* __restrict__ out_dec,
                     double* __restrict__ dloss) {
  extern __shared__ char sm[];
  _Float16* A16   = (_Float16*)sm;                     // [32 Ksub][128 rows][8h] 64 KB
  _Float16* Bs    = (_Float16*)(sm + 65536);           // 2 x [4 sub][512 cols][8h] 32 KB each
  unsigned* cp    = (unsigned*)(sm + 131072);          // [128][CAP]
  int*      cn    = (int*)(sm + 131072 + 128*CAP*4);   // [128]
  unsigned* gmax  = (unsigned*)((char*)cn + 512);      // [128]
  unsigned* bestp = (unsigned*)((char*)gmax + 512);    // [128]

  const int t = threadIdx.x;
  const int wid = t >> 6, ln = t & 63;
  const int l31 = ln & 31, hl = ln >> 5;
  const int rowg = wid >> 2, colg = wid & 3;           // 2 row-groups x 4 col-groups
  const int urow = t >> 2, qo = (t & 3) * 64;          // owner mapping: 4 thr/row
  const int row0 = blockIdx.x * ROWS_B;
  const int mrowA = rowg * 64 + l31;                   // ai=0 row; ai=1 -> +32

  // ---- build A16 (layer-0 input) straight from x ----
  {
    const float4* xg = (const float4*)(x + (size_t)(row0 + urow) * D_DIM + qo);
    #pragma unroll
    for (int j = 0; j < 8; ++j) {
      const float4 a = xg[j*2], b = xg[j*2+1];
      half8 h;
      h[0]=(_Float16)a.x; h[1]=(_Float16)a.y; h[2]=(_Float16)a.z; h[3]=(_Float16)a.w;
      h[4]=(_Float16)b.x; h[5]=(_Float16)b.y; h[6]=(_Float16)b.z; h[7]=(_Float16)b.w;
      const int slot = (t & 3) * 8 + j;
      *(half8*)(A16 + slot*1024 + urow*8) = h;
    }
  }
  if (t < 128) { cn[t] = 0; gmax[t] = 0u; bestp[t] = 0u; }
  int id0 = 0, id1 = 0, id2 = 0, id3 = 0;
  double lloss = 0.0;

  #pragma unroll 1
  for (int l = 0; l < L_NUM; ++l) {
    const char* Bimg = (const char*)cb16 + (size_t)l * (K_CB * D_DIM * 2);
    __syncthreads();                     // A16 + counter resets ordered for everyone
    {                                    // stage chunk 0 -> buf0
      #pragma unroll
      for (int i = 0; i < 4; ++i)
        gl_lds16(Bimg + t*16 + i*8192, (char*)Bs + t*16 + i*8192);
    }

    f32x16 a00, a01, a10, a11, a20, a21, a30, a31;   // acc[bi][ai], named (rule #20)

    #pragma unroll 1
    for (int g = 0; g < 32; ++g) {
      // barrier 1: every wave finished reading buf[(g+1)&1] (as chunk g-1)
      __builtin_amdgcn_s_barrier();
      if (g < 31) {                      // issue stage(g+1); never drain it here
        char* dst = (char*)Bs + ((g + 1) & 1) * 32768;
        const char* src = Bimg + (size_t)(g + 1) * 32768;
        #pragma unroll
        for (int i = 0; i < 4; ++i)
          gl_lds16(src + t*16 + i*8192, dst + t*16 + i*8192);
        asm volatile("s_waitcnt vmcnt(4)" ::: "memory");   // stage(g) landed
      } else {
        asm volatile("s_waitcnt vmcnt(0)" ::: "memory");   // last chunk
      }
      // barrier 2: all waves' share of buf[g&1] landed
      __builtin_amdgcn_s_barrier();

      if ((g & 7) == 0) {
        #pragma unroll
        for (int e = 0; e < 16; ++e) {
          a00[e]=0.f; a01[e]=0.f; a10[e]=0.f; a11[e]=0.f;
          a20[e]=0.f; a21[e]=0.f; a30[e]=0.f; a31[e]=0.f;
        }
      }
      const _Float16* Bb = Bs + (g & 1) * 16384;
      const int kc = g & 7;
      #pragma unroll
      for (int ks2 = 0; ks2 < 2; ++ks2) {
        const int sb = ks2*2 + hl;
        const int sa = kc*4 + sb;
        const half8 af0 = *(const half8*)(A16 + sa*1024 + mrowA*8);
        const half8 af1 = *(const half8*)(A16 + sa*1024 + (mrowA + 32)*8);
        const half8 bf0 = *(const half8*)(Bb + sb*4096 + (colg*128 +  0 + l31)*8);
        const half8 bf1 = *(const half8*)(Bb + sb*4096 + (colg*128 + 32 + l31)*8);
        const half8 bf2 = *(const half8*)(Bb + sb*4096 + (colg*128 + 64 + l31)*8);
        const half8 bf3 = *(const half8*)(Bb + sb*4096 + (colg*128 + 96 + l31)*8);
        a00 = __builtin_amdgcn_mfma_f32_32x32x16_f16(bf0, af0, a00, 0, 0, 0);
        a01 = __builtin_amdgcn_mfma_f32_32x32x16_f16(bf0, af1, a01, 0, 0, 0);
        a10 = __builtin_amdgcn_mfma_f32_32x32x16_f16(bf1, af0, a10, 0, 0, 0);
        a11 = __builtin_amdgcn_mfma_f32_32x32x16_f16(bf1, af1, a11, 0, 0, 0);
        a20 = __builtin_amdgcn_mfma_f32_32x32x16_f16(bf2, af0, a20, 0, 0, 0);
        a21 = __builtin_amdgcn_mfma_f32_32x32x16_f16(bf2, af1, a21, 0, 0, 0);
        a30 = __builtin_amdgcn_mfma_f32_32x32x16_f16(bf3, af0, a30, 0, 0, 0);
        a31 = __builtin_amdgcn_mfma_f32_32x32x16_f16(bf3, af1, a31, 0, 0, 0);
      }
      if ((g & 7) == 7) {                // epilogue per 512-col tile (lane-local rows)
        const int ct = g >> 3;
        {                                // ai = 0
          const int mrow = mrowA;
          const float mm = vmax16_4(a00, a10, a20, a30);
          atomicMax(&gmax[mrow], fenc(mm));
          const float thr = fdec(gmax[mrow]) - WACC;   // stale read = superset-safe
          COLL(a00, 0, mrow, thr, ct) COLL(a10, 1, mrow, thr, ct)
          COLL(a20, 2, mrow, thr, ct) COLL(a30, 3, mrow, thr, ct)
        }
        {                                // ai = 1
          const int mrow = mrowA + 32;
          const float mm = vmax16_4(a01, a11, a21, a31);
          atomicMax(&gmax[mrow], fenc(mm));
          const float thr = fdec(gmax[mrow]) - WACC;
          COLL(a01, 0, mrow, thr, ct) COLL(a11, 1, mrow, thr, ct)
          COLL(a21, 2, mrow, thr, ct) COLL(a31, 3, mrow, thr, ct)
        }
      }
    }
    __syncthreads();                     // epilogue pushes visible to tail

    // ---- tail: recompute exact fp32 residual, filter, double re-rank, update ----
    {
      float r[64];
      {
        const float4* xg = (const float4*)(x + (size_t)(row0 + urow)*D_DIM + qo);
        #pragma unroll
        for (int i = 0; i < 16; ++i) {
          const float4 a = xg[i];
          r[i*4+0]=a.x; r[i*4+1]=a.y; r[i*4+2]=a.z; r[i*4+3]=a.w;
        }
      }
      #pragma unroll 1
      for (int j = 0; j < l; ++j) {      // sequential subtraction = reference rounding
        const int pj = (j==0) ? id0 : (j==1) ? id1 : (j==2) ? id2 : id3;
        const float4* qg = (const float4*)(cb + ((size_t)j*K_CB + pj)*D_DIM + qo);
        #pragma unroll
        for (int i = 0; i < 16; ++i) {
          const float4 a = qg[i];
          r[i*4+0]-=a.x; r[i*4+1]-=a.y; r[i*4+2]-=a.z; r[i*4+3]-=a.w;
        }
      }
      const float thr2 = fdec(gmax[urow]) - WACC2;
      const int m = min(cn[urow], CAP);
      double bsc = (double)INFINITY; int bidx = 0x7fffffff;
      #pragma unroll 1
      for (int j = 0; j <= m; ++j) {     // j==m: bestp fallback, always ranked
        const unsigned p = (j < m) ? cp[urow*CAP + j] : bestp[urow];
        const float v = (float)(p >> 11) * (1.f/16384.f) - 64.f;
        if (j < m && v < thr2) continue; // uniform within the 4-thread row group
        const int cidx = (int)(p & 2047u);
        const float4* cpn = (const float4*)(cbn + ((size_t)l*K_CB + cidx)*D_DIM + qo);
        double s = 0.0, n2 = 0.0;
        #pragma unroll
        for (int i = 0; i < 16; ++i) {
          const float4 a = cpn[i];
          s  = fma((double)r[i*4+0], (double)a.x, s);
          s  = fma((double)r[i*4+1], (double)a.y, s);
          s  = fma((double)r[i*4+2], (double)a.z, s);
          s  = fma((double)r[i*4+3], (double)a.w, s);
          n2 = fma((double)a.x, (double)a.x, n2);
          n2 = fma((double)a.y, (double)a.y, n2);
          n2 = fma((double)a.z, (double)a.z, n2);
          n2 = fma((double)a.w, (double)a.w, n2);
        }
        s  += __shfl_xor(s, 1, 64);  s  += __shfl_xor(s, 2, 64);
        n2 += __shfl_xor(n2, 1, 64); n2 += __shfl_xor(n2, 2, 64);
        const double sc = -2.0 * s + n2;
        if (sc < bsc || (sc == bsc && cidx < bidx)) { bsc = sc; bidx = cidx; }
      }
      bidx &= 2047;                      // provably valid; belt-and-braces
      if (l == 0) id0 = bidx; else if (l == 1) id1 = bidx;
      else if (l == 2) id2 = bidx; else id3 = bidx;
      if ((t & 3) == 0) out_ids[(size_t)(row0 + urow)*L_NUM + l] = (float)bidx;

      // r -= raw q ; loss += ||r_new||^2 ; A16 for next layer
      const float4* qg = (const float4*)(cb + ((size_t)l*K_CB + bidx)*D_DIM + qo);
      #pragma unroll
      for (int i = 0; i < 16; ++i) {
        const float4 q = qg[i];
        r[i*4+0] -= q.x; r[i*4+1] -= q.y; r[i*4+2] -= q.z; r[i*4+3] -= q.w;
        lloss += (double)r[i*4+0]*r[i*4+0] + (double)r[i*4+1]*r[i*4+1]
               + (double)r[i*4+2]*r[i*4+2] + (double)r[i*4+3]*r[i*4+3];
      }
      if (l < 3) {
        #pragma unroll
        for (int j = 0; j < 8; ++j) {
          half8 h;
          #pragma unroll
          for (int e = 0; e < 8; ++e) h[e] = (_Float16)r[j*8+e];
          const int slot = (t & 3) * 8 + j;
          *(half8*)(A16 + slot*1024 + urow*8) = h;
        }
      }
    }
    __syncthreads();                     // tail reads of cp/gmax/bestp retired
    if (l < 3 && t < 128) { cn[t] = 0; gmax[t] = 0u; bestp[t] = 0u; }
    // layer-top __syncthreads separates resets/A16 writes from next pushes
  }

  // ---- decoded = ((q0+q1)+q2)+q3 sequential fp32 (reference rounding) ----
  {
    float dec[64];
    #pragma unroll
    for (int l2 = 0; l2 < L_NUM; ++l2) {
      const int idl = (l2 == 0) ? id0 : (l2 == 1) ? id1 : (l2 == 2) ? id2 : id3;
      const float4* qg = (const float4*)(cb + ((size_t)l2*K_CB + idl)*D_DIM + qo);
      #pragma unroll
      for (int i = 0; i < 16; ++i) {
        const float4 q = qg[i];
        if (l2 == 0) { dec[i*4+0]=q.x; dec[i*4+1]=q.y; dec[i*4+2]=q.z; dec[i*4+3]=q.w; }
        else { dec[i*4+0]+=q.x; dec[i*4+1]+=q.y; dec[i*4+2]+=q.z; dec[i*4+3]+=q.w; }
      }
    }
    float4* dg = (float4*)(out_dec + (size_t)(row0 + urow)*D_DIM + qo);
    #pragma unroll
    for (int i = 0; i < 16; ++i)
      dg[i] = make_float4(dec[i*4+0], dec[i*4+1], dec[i*4+2], dec[i*4+3]);
  }

  // ---- loss reduction (lw overlays cp; all cp reads retired by last barrier) ----
  double* lw = (double*)cp;
  #pragma unroll
  for (int m = 1; m < 64; m <<= 1) lloss += __shfl_xor(lloss, m, 64);
  if (ln == 0) lw[wid] = lloss;
  __syncthreads();
  if (t == 0) {
    double s2 = 0.0;
    #pragma unroll
    for (int j = 0; j < 8; ++j) s2 += lw[j];
    atomicAdd(dloss, s2);
  }
}

__global__ void rq_fin_kernel(const double* __restrict__ dls, float* __restrict__ out_loss) {
  // loss = sum_l (1 + BETA) * ||r-q||^2 / n_elem  (codebook and commitment terms equal)
  out_loss[0] = (float)(dls[0] * 1.25 / 8388608.0);
}

extern "C" void kernel_launch(void* const* d_in, const int* in_sizes, int n_in,
                              void* d_out, int out_size, void* d_ws, size_t ws_size,
                              hipStream_t stream) {
  const float* x  = (const float*)d_in[0];
  const float* cb = (const float*)d_in[1];
  float* out      = (float*)d_out;
  float* out_ids  = out;                                   // [N][4] as float
  float* out_dec  = out + (size_t)N_ROWS * L_NUM;          // [N][256]
  float* out_loss = out_dec + (size_t)N_ROWS * D_DIM;

  char* w = (char*)d_ws;
  double* dls = (double*)w;                   w += 256;
  float* cbn = (float*)w;                     w += (size_t)L_NUM*K_CB*D_DIM*4;
  _Float16* cb16 = (_Float16*)w;              w += (size_t)L_NUM*K_CB*D_DIM*2;

  hipMemsetAsync(dls, 0, sizeof(double), stream);
  prep_all_kernel<<<L_NUM*K_CB, 64, 0, stream>>>(cb, cbn, cb16);

  const size_t smem = 65536 + 65536 + 128*CAP*4 + 512 + 512 + 512;   // 153088 B
  hipFuncSetAttribute(reinterpret_cast<const void*>(rq_fused_kernel),
                      hipFuncAttributeMaxDynamicSharedMemorySize, (int)smem);
  rq_fused_kernel<<<N_ROWS/ROWS_B, 512, smem, stream>>>(x, cb, cbn, cb16,
                                                        out_ids, out_dec, dls);
  rq_fin_kernel<<<1, 1, 0, stream>>>(dls, out_loss);
}